// Round 4
// baseline (407.503 us; speedup 1.0000x reference)
//
#include <hip/hip_runtime.h>
#include <hip/hip_bf16.h>

// loss = (1/C) * sum_i log( sum_j exp(<x_i,x_j>/T) ),  x: [16384, 256] fp32, unit rows.
// R3: SYMMETRY — sim = X X^T is symmetric, exp elementwise. Compute only lower-triangle
// 256x256 tiles (2080 of 4096): off-diag tile adds row-sums to band rb AND col-sums to
// band cb (atomicAdd into one partial[16384]). Halves MFMA + exp work.
// Inner loop unchanged from R2: fragment-major LDS B (lane-linear ds_read_b128, zero
// bank conflicts), counted vmcnt(8) double-buffer, A pinned in regs, scale pre-folded.

#define N_ROWS 16384
#define KD     256
#define BM     256                    // tile = 256 rows x 256 cols; 4 waves x 64 rows
#define BN     64
#define NT     (N_ROWS / BM)          // 64 bands
#define NITER  (BM / BN)              // 4

// exp(sim/T) = exp2( dot * (1/T)*log2 e ); sqrt(2.88539...) folded into BOTH operands.
#define SCALE_SQRT 1.6986436f

typedef short short8 __attribute__((ext_vector_type(8)));   // 8 bf16 = 4 VGPRs
typedef float f32x4  __attribute__((ext_vector_type(4)));

typedef __attribute__((address_space(3))) void       lds_void;
typedef const __attribute__((address_space(1))) void gm_void;

__device__ __forceinline__ float fast_exp2(float x) {
#if __has_builtin(__builtin_amdgcn_exp2f)
    return __builtin_amdgcn_exp2f(x);
#else
    return exp2f(x);
#endif
}

__device__ __forceinline__ void gll16(const void* g, void* l) {
    __builtin_amdgcn_global_load_lds((gm_void*)g, (lds_void*)l, 16, 0, 0);
}

// ---------------- fp32 -> bf16 (RNE, pre-scaled) + zero-init of accumulators ----------------
__global__ void convert_kernel(const float* __restrict__ x, unsigned short* __restrict__ xb,
                               float* __restrict__ partial, float* __restrict__ out) {
    const int bx = blockIdx.x, tid = threadIdx.x;
    if (bx < N_ROWS / 256) partial[bx * 256 + tid] = 0.f;   // zero partial[16384]
    if (bx == N_ROWS / 256 && tid == 0) out[0] = 0.f;       // zero output accumulator
    int i = (bx * 256 + tid) * 4;
    float4 v = *(const float4*)(x + i);
    ushort4 o;
    {
        unsigned int u;
        u = __float_as_uint(v.x * SCALE_SQRT); u += 0x7fff + ((u >> 16) & 1); o.x = (unsigned short)(u >> 16);
        u = __float_as_uint(v.y * SCALE_SQRT); u += 0x7fff + ((u >> 16) & 1); o.y = (unsigned short)(u >> 16);
        u = __float_as_uint(v.z * SCALE_SQRT); u += 0x7fff + ((u >> 16) & 1); o.z = (unsigned short)(u >> 16);
        u = __float_as_uint(v.w * SCALE_SQRT); u += 0x7fff + ((u >> 16) & 1); o.w = (unsigned short)(u >> 16);
    }
    *(ushort4*)(xb + i) = o;
}

// ---------------- main fused kernel: one lower-triangle 256x256 tile per block ----------------
// 256 thr = 4 waves. Wave w: A rows [r0 + w*64, +64) pinned in registers.
// B tile (64 cols x K=256) double-buffered in LDS, fragment-major (1KB per MFMA frag,
// lane slot = lane*16 -> lane-linear ds_read_b128, zero bank conflicts).
__global__ __launch_bounds__(256, 2)
void simloss_main(const unsigned short* __restrict__ xb, float* __restrict__ partial) {
    const int bx = blockIdx.x;
    const int rb = bx >> 6;                     // row band 0..63
    const int cb = bx & 63;                     // col band 0..63
    if (cb > rb) return;                        // lower triangle only
    const bool diag = (rb == cb);

    __shared__ __align__(128) char smem[65536]; // 2 x 32KB B double-buffer

    const int tid  = threadIdx.x;
    const int lane = tid & 63;
    const int w    = tid >> 6;                  // 0..3
    const int r0 = rb * BM;
    const int c0 = cb * BM;

    const int l15 = lane & 15;
    const int lg  = lane >> 4;                  // 0..3

    // ---- A fragments (mfma_16x16x32 A: row = lane&15, k = kt*32 + (lane>>4)*8 + j) ----
    short8 afrag[4][8];
    #pragma unroll
    for (int m = 0; m < 4; ++m) {
        const unsigned short* arow = xb + (size_t)(r0 + w * 64 + m * 16 + l15) * KD + lg * 8;
        #pragma unroll
        for (int kt = 0; kt < 8; ++kt)
            afrag[m][kt] = *(const short8*)(arow + kt * 32);
    }
    #pragma unroll
    for (int m = 0; m < 4; ++m)
        #pragma unroll
        for (int kt = 0; kt < 8; ++kt)
            asm volatile("" : "+v"(afrag[m][kt]));

    // ---- B staging: wave w stages frags (ct=w, kt=0..7): 8 gll16 per 64-col tile ----
    const unsigned short* bsrc0 = xb + (size_t)(c0 + w * 16 + l15) * KD + lg * 8;
    char* const ldst0 = smem + (w * 8) * 1024;

    auto stageB = [&](int buf, int it2) {
        const unsigned short* s = bsrc0 + (size_t)it2 * (BN * KD);
        char* dst = ldst0 + buf * 32768;
        #pragma unroll
        for (int kt = 0; kt < 8; ++kt)
            gll16(s + kt * 32, dst + kt * 1024);
    };

    float rowsum[4][4] = {{0.f}};

    stageB(0, 0);

    #pragma unroll
    for (int it = 0; it < NITER; ++it) {
        const int cur = it & 1;
        if (it + 1 < NITER) {
            stageB(cur ^ 1, it + 1);
            asm volatile("s_waitcnt vmcnt(8)" ::: "memory");
        } else {
            asm volatile("s_waitcnt vmcnt(0)" ::: "memory");
        }
        __builtin_amdgcn_s_barrier();
        asm volatile("" ::: "memory");

        const char* bbase = smem + cur * 32768;
        #pragma unroll
        for (int ct = 0; ct < 4; ++ct) {
            short8 bfrag[8];
            #pragma unroll
            for (int kt = 0; kt < 8; ++kt)
                bfrag[kt] = *(const short8*)(bbase + (ct * 8 + kt) * 1024 + lane * 16);
            f32x4 acc[4];
            #pragma unroll
            for (int m = 0; m < 4; ++m) acc[m] = (f32x4){0.f, 0.f, 0.f, 0.f};
            #pragma unroll
            for (int kt = 0; kt < 8; ++kt)
                #pragma unroll
                for (int m = 0; m < 4; ++m)
                    acc[m] = __builtin_amdgcn_mfma_f32_16x16x32_bf16(afrag[m][kt], bfrag[kt], acc[m], 0, 0, 0);
            // C/D: col = lane&15, row-in-16 = (lane>>4)*4 + r
            float csum = 0.f;
            #pragma unroll
            for (int m = 0; m < 4; ++m)
                #pragma unroll
                for (int r = 0; r < 4; ++r) {
                    float e = fast_exp2(acc[m][r]);
                    rowsum[m][r] += e;
                    csum += e;
                }
            if (!diag) {   // col-sums feed the mirrored rows (band cb)
                csum += __shfl_xor(csum, 16);
                csum += __shfl_xor(csum, 32);
                if (lg == 0)
                    atomicAdd(partial + c0 + it * BN + ct * 16 + l15, csum);
            }
        }

        asm volatile("" ::: "memory");
        __builtin_amdgcn_s_barrier();
        asm volatile("" ::: "memory");
    }

    // ---- row-sums: reduce over the 16 column-lanes, atomic into partial ----
    #pragma unroll
    for (int m = 0; m < 4; ++m)
        #pragma unroll
        for (int r = 0; r < 4; ++r) {
            float v = rowsum[m][r];
            v += __shfl_xor(v, 1);
            v += __shfl_xor(v, 2);
            v += __shfl_xor(v, 4);
            v += __shfl_xor(v, 8);
            if (l15 == 0)
                atomicAdd(partial + r0 + w * 64 + m * 16 + lg * 4 + r, v);
        }
}

// ---------------- finalize: loss = sum_i log(partial_i) / 100 (parallel) ----------------
__global__ void finalize_kernel(const float* __restrict__ partial, float* __restrict__ out) {
    int i = blockIdx.x * 256 + threadIdx.x;      // one row per thread, 64 blocks
    float v = logf(partial[i]);
    #pragma unroll
    for (int off = 1; off < 64; off <<= 1) v += __shfl_xor(v, off);
    __shared__ float red[4];
    if ((threadIdx.x & 63) == 0) red[threadIdx.x >> 6] = v;
    __syncthreads();
    if (threadIdx.x == 0)
        atomicAdd(out, (red[0] + red[1] + red[2] + red[3]) * 0.01f);
}

extern "C" void kernel_launch(void* const* d_in, const int* in_sizes, int n_in,
                              void* d_out, int out_size, void* d_ws, size_t ws_size,
                              hipStream_t stream) {
    const float* x = (const float*)d_in[0];
    unsigned short* xb = (unsigned short*)d_ws;                           // 8 MB bf16 (pre-scaled)
    float* partial = (float*)((char*)d_ws + (size_t)N_ROWS * KD * 2);     // 16384 f32 accumulators
    float* out = (float*)d_out;

    convert_kernel<<<(N_ROWS * KD) / (256 * 4), 256, 0, stream>>>(x, xb, partial, out);
    simloss_main<<<NT * NT, 256, 0, stream>>>(xb, partial);
    finalize_kernel<<<N_ROWS / 256, 256, 0, stream>>>(partial, out);
}

// Round 5
// 257.049 us; speedup vs baseline: 1.5853x; 1.5853x over previous
//
#include <hip/hip_runtime.h>
#include <hip/hip_bf16.h>
#include <math.h>

// loss = (1/C) * sum_i log( sum_j exp(<x_i,x_j>/T) ),  x: [16384, 256] fp32, unit rows.
// R4: symmetry WITHOUT atomics. sim = X X^T symmetric; lower-triangle 256x256 tiles only
// (2080 blocks). Block (rb,cb) writes row-sums to rowacc[cb][band rb] and col-sums to
// rowacc[rb][band cb] — every slot of rowacc[64][16384] has exactly ONE writer (k<=band(j)
// comes from row-path of block (band(j),k); k>band(j) from col-path of block (k,band(j))),
// so plain coalesced stores replace R3's 2.7M device-scope atomics (which caused 322 MB
// of write-through RMW traffic and 358us). Finalize: row j sums its 64 slots, log, reduce.

#define N_ROWS 16384
#define KD     256
#define BM     256                    // tile = 256x256; 4 waves x 64 rows
#define BN     64
#define NT     (N_ROWS / BM)          // 64 bands
#define NITER  (BM / BN)              // 4
#define NBLK   (NT * (NT + 1) / 2)    // 2080 lower-triangle tiles

// exp(sim/T) = exp2( dot * (1/T)*log2 e ); sqrt(2.88539...) folded into BOTH operands.
#define SCALE_SQRT 1.6986436f

typedef short short8 __attribute__((ext_vector_type(8)));   // 8 bf16 = 4 VGPRs
typedef float f32x4  __attribute__((ext_vector_type(4)));

typedef __attribute__((address_space(3))) void       lds_void;
typedef const __attribute__((address_space(1))) void gm_void;

__device__ __forceinline__ float fast_exp2(float x) {
#if __has_builtin(__builtin_amdgcn_exp2f)
    return __builtin_amdgcn_exp2f(x);
#else
    return exp2f(x);
#endif
}

__device__ __forceinline__ void gll16(const void* g, void* l) {
    __builtin_amdgcn_global_load_lds((gm_void*)g, (lds_void*)l, 16, 0, 0);
}

// ---------------- fp32 -> bf16 (RNE, pre-scaled) + zero-init of out ----------------
__global__ void convert_kernel(const float* __restrict__ x, unsigned short* __restrict__ xb,
                               float* __restrict__ out) {
    const int bx = blockIdx.x, tid = threadIdx.x;
    if (bx == 0 && tid == 0) out[0] = 0.f;
    int i = (bx * 256 + tid) * 4;
    float4 v = *(const float4*)(x + i);
    ushort4 o;
    {
        unsigned int u;
        u = __float_as_uint(v.x * SCALE_SQRT); u += 0x7fff + ((u >> 16) & 1); o.x = (unsigned short)(u >> 16);
        u = __float_as_uint(v.y * SCALE_SQRT); u += 0x7fff + ((u >> 16) & 1); o.y = (unsigned short)(u >> 16);
        u = __float_as_uint(v.z * SCALE_SQRT); u += 0x7fff + ((u >> 16) & 1); o.z = (unsigned short)(u >> 16);
        u = __float_as_uint(v.w * SCALE_SQRT); u += 0x7fff + ((u >> 16) & 1); o.w = (unsigned short)(u >> 16);
    }
    *(ushort4*)(xb + i) = o;
}

// ---------------- main fused kernel: one lower-triangle 256x256 tile per block ----------------
// 256 thr = 4 waves. Wave w: A rows [r0 + w*64, +64) pinned in registers.
// B (64 cols x K=256) double-buffered in LDS, fragment-major (1KB/frag, lane-linear
// ds_read_b128 -> zero bank conflicts; per-lane-permuted global src, linear LDS dst).
__global__ __launch_bounds__(256, 2)
void simloss_main(const unsigned short* __restrict__ xb, float* __restrict__ rowacc) {
    // triangular decode: bid -> (rb, cb), cb <= rb
    const int bid = blockIdx.x;
    int rb = (int)((sqrtf(8.f * (float)bid + 1.f) - 1.f) * 0.5f);
    while ((rb + 1) * (rb + 2) / 2 <= bid) ++rb;
    while (rb * (rb + 1) / 2 > bid) --rb;
    const int cb = bid - rb * (rb + 1) / 2;
    const bool diag = (rb == cb);

    __shared__ __align__(128) char smem[65536 + 1024 + 4096];
    float* const rowred = (float*)(smem + 65536);          // [256]
    float* const colred = (float*)(smem + 65536 + 1024);   // [4][256]

    const int tid  = threadIdx.x;
    const int lane = tid & 63;
    const int w    = tid >> 6;                  // 0..3
    const int r0 = rb * BM;
    const int c0 = cb * BM;

    const int l15 = lane & 15;
    const int lg  = lane >> 4;                  // 0..3

    // ---- A fragments (mfma_16x16x32 A: row = lane&15, k = kt*32 + (lane>>4)*8 + j) ----
    short8 afrag[4][8];
    #pragma unroll
    for (int m = 0; m < 4; ++m) {
        const unsigned short* arow = xb + (size_t)(r0 + w * 64 + m * 16 + l15) * KD + lg * 8;
        #pragma unroll
        for (int kt = 0; kt < 8; ++kt)
            afrag[m][kt] = *(const short8*)(arow + kt * 32);
    }
    #pragma unroll
    for (int m = 0; m < 4; ++m)
        #pragma unroll
        for (int kt = 0; kt < 8; ++kt)
            asm volatile("" : "+v"(afrag[m][kt]));

    // ---- B staging: wave w stages frags (ct=w, kt=0..7): 8 gll16 per 64-col tile ----
    const unsigned short* bsrc0 = xb + (size_t)(c0 + w * 16 + l15) * KD + lg * 8;
    char* const ldst0 = smem + (w * 8) * 1024;

    auto stageB = [&](int buf, int it2) {
        const unsigned short* s = bsrc0 + (size_t)it2 * (BN * KD);
        char* dst = ldst0 + buf * 32768;
        #pragma unroll
        for (int kt = 0; kt < 8; ++kt)
            gll16(s + kt * 32, dst + kt * 1024);
    };

    float rowsum[4][4] = {{0.f}};
    float ccol[16];                              // per-(it,ct) wave col-sums (post-shfl)

    stageB(0, 0);

    #pragma unroll
    for (int it = 0; it < NITER; ++it) {
        const int cur = it & 1;
        if (it + 1 < NITER) {
            stageB(cur ^ 1, it + 1);
            asm volatile("s_waitcnt vmcnt(8)" ::: "memory");
        } else {
            asm volatile("s_waitcnt vmcnt(0)" ::: "memory");
        }
        __builtin_amdgcn_s_barrier();
        asm volatile("" ::: "memory");

        const char* bbase = smem + cur * 32768;
        #pragma unroll
        for (int ct = 0; ct < 4; ++ct) {
            short8 bfrag[8];
            #pragma unroll
            for (int kt = 0; kt < 8; ++kt)
                bfrag[kt] = *(const short8*)(bbase + (ct * 8 + kt) * 1024 + lane * 16);
            f32x4 acc[4];
            #pragma unroll
            for (int m = 0; m < 4; ++m) acc[m] = (f32x4){0.f, 0.f, 0.f, 0.f};
            #pragma unroll
            for (int kt = 0; kt < 8; ++kt)
                #pragma unroll
                for (int m = 0; m < 4; ++m)
                    acc[m] = __builtin_amdgcn_mfma_f32_16x16x32_bf16(afrag[m][kt], bfrag[kt], acc[m], 0, 0, 0);
            // C/D: col = lane&15, row-in-16 = (lane>>4)*4 + r
            float csum = 0.f;
            #pragma unroll
            for (int m = 0; m < 4; ++m)
                #pragma unroll
                for (int r = 0; r < 4; ++r) {
                    float e = fast_exp2(acc[m][r]);
                    rowsum[m][r] += e;
                    csum += e;
                }
            if (!diag) {                         // wave col-sum for 16 cols of this (it,ct)
                csum += __shfl_xor(csum, 16);
                csum += __shfl_xor(csum, 32);
                ccol[it * 4 + ct] = csum;        // static index (fully unrolled)
            }
        }

        asm volatile("" ::: "memory");
        __builtin_amdgcn_s_barrier();
        asm volatile("" ::: "memory");
    }

    // ---- per-wave results -> LDS (no atomics anywhere) ----
    if (!diag && lg == 0) {
        #pragma unroll
        for (int idx = 0; idx < 16; ++idx)
            colred[w * 256 + (idx >> 2) * 64 + (idx & 3) * 16 + l15] = ccol[idx];
    }
    #pragma unroll
    for (int m = 0; m < 4; ++m)
        #pragma unroll
        for (int r = 0; r < 4; ++r) {
            float v = rowsum[m][r];
            v += __shfl_xor(v, 1);
            v += __shfl_xor(v, 2);
            v += __shfl_xor(v, 4);
            v += __shfl_xor(v, 8);
            if (l15 == 0) rowred[w * 64 + m * 16 + lg * 4 + r] = v;
        }
    __syncthreads();

    // ---- coalesced single-writer stores ----
    rowacc[(size_t)cb * N_ROWS + r0 + tid] = rowred[tid];                      // k=cb <= rb
    if (!diag) {
        float cs = colred[tid] + colred[256 + tid] + colred[512 + tid] + colred[768 + tid];
        rowacc[(size_t)rb * N_ROWS + c0 + tid] = cs;                           // k=rb > cb
    }
}

// ---------------- finalize: loss = sum_i log( sum_k rowacc[k][i] ) / 100 ----------------
__global__ void finalize_kernel(const float* __restrict__ rowacc, float* __restrict__ out) {
    int i = blockIdx.x * 256 + threadIdx.x;      // one row per thread, 64 blocks
    float s = 0.f;
    #pragma unroll 8
    for (int k = 0; k < NT; ++k) s += rowacc[(size_t)k * N_ROWS + i];
    float v = logf(s);
    #pragma unroll
    for (int off = 1; off < 64; off <<= 1) v += __shfl_xor(v, off);
    __shared__ float red[4];
    if ((threadIdx.x & 63) == 0) red[threadIdx.x >> 6] = v;
    __syncthreads();
    if (threadIdx.x == 0)
        atomicAdd(out, (red[0] + red[1] + red[2] + red[3]) * 0.01f);
}

extern "C" void kernel_launch(void* const* d_in, const int* in_sizes, int n_in,
                              void* d_out, int out_size, void* d_ws, size_t ws_size,
                              hipStream_t stream) {
    const float* x = (const float*)d_in[0];
    unsigned short* xb = (unsigned short*)d_ws;                           // 8 MB bf16 (pre-scaled)
    float* rowacc = (float*)((char*)d_ws + (size_t)N_ROWS * KD * 2);      // 64 x 16384 f32 (4 MB)
    float* out = (float*)d_out;

    convert_kernel<<<(N_ROWS * KD) / (256 * 4), 256, 0, stream>>>(x, xb, out);
    simloss_main<<<NBLK, 256, 0, stream>>>(xb, rowacc);
    finalize_kernel<<<N_ROWS / 256, 256, 0, stream>>>(rowacc, out);
}

// Round 6
// 162.898 us; speedup vs baseline: 2.5016x; 1.5780x over previous
//
#include <hip/hip_runtime.h>
#include <hip/hip_bf16.h>
#include <math.h>

// loss = (1/C) * sum_i log( sum_j exp(<x_i,x_j>/T) ),  x: [16384, 256] fp32, unit rows.
// R5: R4's no-atomic symmetry scheme + fix the REAL R3/R4 bottleneck: register spill.
// (R3/R4 WRITE_SIZE ~322 MB was scratch spill traffic, not atomics — identical with and
// without them.) Spill cause: fully-unrolled NITER=4 loop + ccol[16] live array pushed
// the live set past the 256-reg cap, so A-frags fell out of AGPRs into scratch.
// Fix: rolled it-loop (#pragma unroll 1, dynamic cur) and col-sums stored straight to
// LDS inside the loop (no register array) — restores R2's allocation (A in AGPRs).

#define N_ROWS 16384
#define KD     256
#define BM     256                    // tile = 256x256; 4 waves x 64 rows
#define BN     64
#define NT     (N_ROWS / BM)          // 64 bands
#define NITER  (BM / BN)              // 4
#define NBLK   (NT * (NT + 1) / 2)    // 2080 lower-triangle tiles

// exp(sim/T) = exp2( dot * (1/T)*log2 e ); sqrt(2.88539...) folded into BOTH operands.
#define SCALE_SQRT 1.6986436f

typedef short short8 __attribute__((ext_vector_type(8)));   // 8 bf16 = 4 VGPRs
typedef float f32x4  __attribute__((ext_vector_type(4)));

typedef __attribute__((address_space(3))) void       lds_void;
typedef const __attribute__((address_space(1))) void gm_void;

__device__ __forceinline__ float fast_exp2(float x) {
#if __has_builtin(__builtin_amdgcn_exp2f)
    return __builtin_amdgcn_exp2f(x);
#else
    return exp2f(x);
#endif
}

__device__ __forceinline__ void gll16(const void* g, void* l) {
    __builtin_amdgcn_global_load_lds((gm_void*)g, (lds_void*)l, 16, 0, 0);
}

// ---------------- fp32 -> bf16 (RNE, pre-scaled) + zero-init of out ----------------
__global__ void convert_kernel(const float* __restrict__ x, unsigned short* __restrict__ xb,
                               float* __restrict__ out) {
    const int bx = blockIdx.x, tid = threadIdx.x;
    if (bx == 0 && tid == 0) out[0] = 0.f;
    int i = (bx * 256 + tid) * 4;
    float4 v = *(const float4*)(x + i);
    ushort4 o;
    {
        unsigned int u;
        u = __float_as_uint(v.x * SCALE_SQRT); u += 0x7fff + ((u >> 16) & 1); o.x = (unsigned short)(u >> 16);
        u = __float_as_uint(v.y * SCALE_SQRT); u += 0x7fff + ((u >> 16) & 1); o.y = (unsigned short)(u >> 16);
        u = __float_as_uint(v.z * SCALE_SQRT); u += 0x7fff + ((u >> 16) & 1); o.z = (unsigned short)(u >> 16);
        u = __float_as_uint(v.w * SCALE_SQRT); u += 0x7fff + ((u >> 16) & 1); o.w = (unsigned short)(u >> 16);
    }
    *(ushort4*)(xb + i) = o;
}

// ---------------- main fused kernel: one lower-triangle 256x256 tile per block ----------------
// 256 thr = 4 waves. Wave w: A rows [r0 + w*64, +64) pinned in regs/AGPRs.
// B (64 cols x K=256) double-buffered in LDS, fragment-major (1KB/frag, lane-linear
// ds_read_b128 -> zero bank conflicts; per-lane-permuted global src, linear LDS dst).
__global__ __launch_bounds__(256, 2)
void simloss_main(const unsigned short* __restrict__ xb, float* __restrict__ rowacc) {
    // triangular decode: bid -> (rb, cb), cb <= rb
    const int bid = blockIdx.x;
    int rb = (int)((sqrtf(8.f * (float)bid + 1.f) - 1.f) * 0.5f);
    while ((rb + 1) * (rb + 2) / 2 <= bid) ++rb;
    while (rb * (rb + 1) / 2 > bid) --rb;
    const int cb = bid - rb * (rb + 1) / 2;
    const bool diag = (rb == cb);

    __shared__ __align__(128) char smem[65536 + 1024 + 4096];
    float* const rowred = (float*)(smem + 65536);          // [256]
    float* const colred = (float*)(smem + 65536 + 1024);   // [4][256] per-wave col-sums

    const int tid  = threadIdx.x;
    const int lane = tid & 63;
    const int w    = tid >> 6;                  // 0..3
    const int r0 = rb * BM;
    const int c0 = cb * BM;

    const int l15 = lane & 15;
    const int lg  = lane >> 4;                  // 0..3

    // ---- A fragments (mfma_16x16x32 A: row = lane&15, k = kt*32 + (lane>>4)*8 + j) ----
    short8 afrag[4][8];
    #pragma unroll
    for (int m = 0; m < 4; ++m) {
        const unsigned short* arow = xb + (size_t)(r0 + w * 64 + m * 16 + l15) * KD + lg * 8;
        #pragma unroll
        for (int kt = 0; kt < 8; ++kt)
            afrag[m][kt] = *(const short8*)(arow + kt * 32);
    }
    #pragma unroll
    for (int m = 0; m < 4; ++m)
        #pragma unroll
        for (int kt = 0; kt < 8; ++kt)
            asm volatile("" : "+v"(afrag[m][kt]));   // pin; rolled loop keeps these in AGPRs

    // ---- B staging: wave w stages frags (ct=w, kt=0..7): 8 gll16 per 64-col tile ----
    const unsigned short* bsrc0 = xb + (size_t)(c0 + w * 16 + l15) * KD + lg * 8;
    char* const ldst0 = smem + (w * 8) * 1024;

    auto stageB = [&](int buf, int it2) {
        const unsigned short* s = bsrc0 + (size_t)it2 * (BN * KD);
        char* dst = ldst0 + buf * 32768;
        #pragma unroll
        for (int kt = 0; kt < 8; ++kt)
            gll16(s + kt * 32, dst + kt * 1024);
    };

    float rowsum[4][4] = {{0.f}};

    stageB(0, 0);

    #pragma unroll 1                             // MUST stay rolled: unrolling spills A to scratch
    for (int it = 0; it < NITER; ++it) {
        const int cur = it & 1;
        if (it + 1 < NITER) {
            stageB(cur ^ 1, it + 1);
            asm volatile("s_waitcnt vmcnt(8)" ::: "memory");
        } else {
            asm volatile("s_waitcnt vmcnt(0)" ::: "memory");
        }
        __builtin_amdgcn_s_barrier();
        asm volatile("" ::: "memory");

        const char* bbase = smem + cur * 32768;
        #pragma unroll
        for (int ct = 0; ct < 4; ++ct) {
            short8 bfrag[8];
            #pragma unroll
            for (int kt = 0; kt < 8; ++kt)
                bfrag[kt] = *(const short8*)(bbase + (ct * 8 + kt) * 1024 + lane * 16);
            f32x4 acc[4];
            #pragma unroll
            for (int m = 0; m < 4; ++m) acc[m] = (f32x4){0.f, 0.f, 0.f, 0.f};
            #pragma unroll
            for (int kt = 0; kt < 8; ++kt)
                #pragma unroll
                for (int m = 0; m < 4; ++m)
                    acc[m] = __builtin_amdgcn_mfma_f32_16x16x32_bf16(afrag[m][kt], bfrag[kt], acc[m], 0, 0, 0);
            // C/D: col = lane&15, row-in-16 = (lane>>4)*4 + r
            float csum = 0.f;
            #pragma unroll
            for (int m = 0; m < 4; ++m)
                #pragma unroll
                for (int r = 0; r < 4; ++r) {
                    float e = fast_exp2(acc[m][r]);
                    rowsum[m][r] += e;
                    csum += e;
                }
            if (!diag) {                         // col-sum for these 16 cols -> LDS (no reg array)
                csum += __shfl_xor(csum, 16);
                csum += __shfl_xor(csum, 32);
                if (lg == 0)
                    colred[w * 256 + it * 64 + ct * 16 + l15] = csum;
            }
        }

        asm volatile("" ::: "memory");
        __builtin_amdgcn_s_barrier();
        asm volatile("" ::: "memory");
    }

    // ---- row-sums -> LDS, then coalesced single-writer stores ----
    #pragma unroll
    for (int m = 0; m < 4; ++m)
        #pragma unroll
        for (int r = 0; r < 4; ++r) {
            float v = rowsum[m][r];
            v += __shfl_xor(v, 1);
            v += __shfl_xor(v, 2);
            v += __shfl_xor(v, 4);
            v += __shfl_xor(v, 8);
            if (l15 == 0) rowred[w * 64 + m * 16 + lg * 4 + r] = v;
        }
    __syncthreads();

    rowacc[(size_t)cb * N_ROWS + r0 + tid] = rowred[tid];              // slot k=cb, band rb
    if (!diag) {
        float cs = colred[tid] + colred[256 + tid] + colred[512 + tid] + colred[768 + tid];
        rowacc[(size_t)rb * N_ROWS + c0 + tid] = cs;                   // slot k=rb, band cb
    }
}

// ---------------- finalize: loss = sum_i log( sum_k rowacc[k][i] ) / 100 ----------------
__global__ void finalize_kernel(const float* __restrict__ rowacc, float* __restrict__ out) {
    int i = blockIdx.x * 256 + threadIdx.x;      // one row per thread, 64 blocks
    float s = 0.f;
    #pragma unroll 8
    for (int k = 0; k < NT; ++k) s += rowacc[(size_t)k * N_ROWS + i];
    float v = logf(s);
    #pragma unroll
    for (int off = 1; off < 64; off <<= 1) v += __shfl_xor(v, off);
    __shared__ float red[4];
    if ((threadIdx.x & 63) == 0) red[threadIdx.x >> 6] = v;
    __syncthreads();
    if (threadIdx.x == 0)
        atomicAdd(out, (red[0] + red[1] + red[2] + red[3]) * 0.01f);
}

extern "C" void kernel_launch(void* const* d_in, const int* in_sizes, int n_in,
                              void* d_out, int out_size, void* d_ws, size_t ws_size,
                              hipStream_t stream) {
    const float* x = (const float*)d_in[0];
    unsigned short* xb = (unsigned short*)d_ws;                           // 8 MB bf16 (pre-scaled)
    float* rowacc = (float*)((char*)d_ws + (size_t)N_ROWS * KD * 2);      // 64 x 16384 f32 (4 MB)
    float* out = (float*)d_out;

    convert_kernel<<<(N_ROWS * KD) / (256 * 4), 256, 0, stream>>>(x, xb, out);
    simloss_main<<<NBLK, 256, 0, stream>>>(xb, rowacc);
    finalize_kernel<<<N_ROWS / 256, 256, 0, stream>>>(rowacc, out);
}

// Round 7
// 149.882 us; speedup vs baseline: 2.7188x; 1.0868x over previous
//
#include <hip/hip_runtime.h>
#include <hip/hip_bf16.h>
#include <math.h>

// loss = (1/C) * sum_i log( sum_j exp(<x_i,x_j>/T) ),  x: [16384, 256] fp32, unit rows.
// R6: R5 at 26% MfmaUtil because 2080 blocks x 4-iter loops never hit steady state
// (prologue/epilogue/barrier amortization; R2's identical inner loop at 32 iters = 53%).
// Fix: global tile partition — 512 blocks (2/CU, one residency round, balanced 4-5
// tiles each, contiguous rb-major), per-row segments with A loaded once per segment,
// rolled loop over 4*ntiles contiguous 64-col iterations. Col-sums flushed per tile
// (slot k=rb); row-sums per segment (slot 64+(b&31); blocks sharing a row span <=17
// ids -> distinct mod 32). rowacc[96][16384] zeroed in convert. No atomics anywhere.

#define N_ROWS 16384
#define KD     256
#define NT     64                     // 256-row bands
#define NTILE  (NT * (NT + 1) / 2)    // 2080 lower-triangle tiles
#define NBLK   512                    // global partition: 65/16 tiles per block
#define NSLOT  96                     // rowacc slots: 0..63 col-path, 64..95 row-path

// exp(sim/T) = exp2( dot * (1/T)*log2 e ); sqrt(2.88539...) folded into BOTH operands.
#define SCALE_SQRT 1.6986436f

typedef short short8 __attribute__((ext_vector_type(8)));   // 8 bf16 = 4 VGPRs
typedef float f32x4  __attribute__((ext_vector_type(4)));

typedef __attribute__((address_space(3))) void       lds_void;
typedef const __attribute__((address_space(1))) void gm_void;

__device__ __forceinline__ float fast_exp2(float x) {
#if __has_builtin(__builtin_amdgcn_exp2f)
    return __builtin_amdgcn_exp2f(x);
#else
    return exp2f(x);
#endif
}

__device__ __forceinline__ void gll16(const void* g, void* l) {
    __builtin_amdgcn_global_load_lds((gm_void*)g, (lds_void*)l, 16, 0, 0);
}

// ---------------- fp32 -> bf16 (RNE, pre-scaled) + zero rowacc/out ----------------
__global__ void convert_kernel(const float* __restrict__ x, unsigned short* __restrict__ xb,
                               float* __restrict__ rowacc, float* __restrict__ out) {
    const int bx = blockIdx.x, tid = threadIdx.x;
    if (bx < (NSLOT * N_ROWS) / 1024)                       // 1536 blocks zero 4 floats each
        *(float4*)(rowacc + (size_t)(bx * 256 + tid) * 4) = (float4){0.f, 0.f, 0.f, 0.f};
    if (bx == 2000 && tid == 0) out[0] = 0.f;
    int i = (bx * 256 + tid) * 4;
    float4 v = *(const float4*)(x + i);
    ushort4 o;
    {
        unsigned int u;
        u = __float_as_uint(v.x * SCALE_SQRT); u += 0x7fff + ((u >> 16) & 1); o.x = (unsigned short)(u >> 16);
        u = __float_as_uint(v.y * SCALE_SQRT); u += 0x7fff + ((u >> 16) & 1); o.y = (unsigned short)(u >> 16);
        u = __float_as_uint(v.z * SCALE_SQRT); u += 0x7fff + ((u >> 16) & 1); o.z = (unsigned short)(u >> 16);
        u = __float_as_uint(v.w * SCALE_SQRT); u += 0x7fff + ((u >> 16) & 1); o.w = (unsigned short)(u >> 16);
    }
    *(ushort4*)(xb + i) = o;
}

// ---------------- main fused kernel: block owns tiles [(b*65)>>4, ((b+1)*65)>>4) ----------------
// 256 thr = 4 waves. Per row-segment: wave w's A rows [rb*256 + w*64, +64) pinned in
// regs/AGPRs; rolled loop over 4*ntiles contiguous 64-col iterations. B double-buffered
// in LDS fragment-major (1KB/frag, lane-linear ds_read_b128 -> zero bank conflicts).
__global__ __launch_bounds__(256, 2)
void simloss_main(const unsigned short* __restrict__ xb, float* __restrict__ rowacc) {
    __shared__ __align__(128) char smem[65536 + 1024 + 4096];
    float* const rowred = (float*)(smem + 65536);          // [256]
    float* const colred = (float*)(smem + 65536 + 1024);   // [4][256]

    const int tid  = threadIdx.x;
    const int lane = tid & 63;
    const int w    = tid >> 6;                  // 0..3
    const int l15  = lane & 15;
    const int lg   = lane >> 4;                 // 0..3
    const int b    = blockIdx.x;

    int t          = (b * 65) >> 4;             // first tile (rb-major order)
    const int tEnd = ((b + 1) * 65) >> 4;       // exclusive
    const int rowSlot = NT + (b & 31);

    int rb = (int)((sqrtf(8.f * (float)t + 1.f) - 1.f) * 0.5f);
    while ((rb + 1) * (rb + 2) / 2 <= t) ++rb;
    while (rb * (rb + 1) / 2 > t) --rb;

    #pragma unroll 1
    while (t < tEnd) {
        while ((rb + 1) * (rb + 2) / 2 <= t) ++rb;          // advance row band
        const int rowStart = rb * (rb + 1) / 2;
        const int cb0 = t - rowStart;
        const int tE  = tEnd - rowStart;
        const int cbE = tE < rb + 1 ? tE : rb + 1;          // exclusive end cb
        const int NI  = (cbE - cb0) * 4;                    // 64-col iterations
        const int r0  = rb * 256;
        const int colblk0 = cb0 * 4;

        auto stageB = [&](int buf, int cblk) {
            const unsigned short* s = xb + (size_t)(cblk * 64 + w * 16 + l15) * KD + lg * 8;
            char* dst = smem + buf * 32768 + (w * 8) * 1024;
            #pragma unroll
            for (int kt = 0; kt < 8; ++kt)
                gll16(s + kt * 32, dst + kt * 1024);
        };
        stageB(0, colblk0);                     // issue B0 BEFORE A so latencies overlap

        // A frags (mfma_16x16x32 A: row = lane&15, k = kt*32 + (lane>>4)*8 + j)
        short8 afrag[4][8];
        #pragma unroll
        for (int m = 0; m < 4; ++m) {
            const unsigned short* ar = xb + (size_t)(r0 + w * 64 + m * 16 + l15) * KD + lg * 8;
            #pragma unroll
            for (int kt = 0; kt < 8; ++kt)
                afrag[m][kt] = *(const short8*)(ar + kt * 32);
        }
        #pragma unroll
        for (int m = 0; m < 4; ++m)
            #pragma unroll
            for (int kt = 0; kt < 8; ++kt)
                asm volatile("" : "+v"(afrag[m][kt]));      // pin (rolled loop -> AGPRs)

        float rowsum[4][4] = {{0.f}};

        #pragma unroll 1                        // MUST stay rolled: unrolling spills A
        for (int fi = 0; fi < NI; ++fi) {
            const int cur = fi & 1;
            if (fi + 1 < NI) {
                stageB(cur ^ 1, colblk0 + fi + 1);
                asm volatile("s_waitcnt vmcnt(8)" ::: "memory");
            } else {
                asm volatile("s_waitcnt vmcnt(0)" ::: "memory");
            }
            __builtin_amdgcn_s_barrier();
            asm volatile("" ::: "memory");

            const char* bbase = smem + cur * 32768;
            #pragma unroll
            for (int ct = 0; ct < 4; ++ct) {
                short8 bfrag[8];
                #pragma unroll
                for (int kt = 0; kt < 8; ++kt)              // lane-linear: zero conflicts
                    bfrag[kt] = *(const short8*)(bbase + (ct * 8 + kt) * 1024 + lane * 16);
                f32x4 acc[4];
                #pragma unroll
                for (int m = 0; m < 4; ++m) acc[m] = (f32x4){0.f, 0.f, 0.f, 0.f};
                #pragma unroll
                for (int kt = 0; kt < 8; ++kt)
                    #pragma unroll
                    for (int m = 0; m < 4; ++m)
                        acc[m] = __builtin_amdgcn_mfma_f32_16x16x32_bf16(afrag[m][kt], bfrag[kt], acc[m], 0, 0, 0);
                // C/D: col = lane&15, row-in-16 = (lane>>4)*4 + r
                float csum = 0.f;
                #pragma unroll
                for (int m = 0; m < 4; ++m)
                    #pragma unroll
                    for (int r = 0; r < 4; ++r) {
                        float e = fast_exp2(acc[m][r]);
                        rowsum[m][r] += e;
                        csum += e;
                    }
                csum += __shfl_xor(csum, 16);
                csum += __shfl_xor(csum, 32);
                if (lg == 0)
                    colred[w * 256 + (fi & 3) * 64 + ct * 16 + l15] = csum;
            }

            asm volatile("" ::: "memory");
            __builtin_amdgcn_s_barrier();
            asm volatile("" ::: "memory");

            if ((fi & 3) == 3) {                // tile boundary: flush col-sums (k=rb)
                const int cb = cb0 + (fi >> 2);
                if (cb != rb) {
                    float cs = colred[tid] + colred[256 + tid] + colred[512 + tid] + colred[768 + tid];
                    rowacc[(size_t)rb * N_ROWS + cb * 256 + tid] = cs;
                }
            }
        }

        // segment epilogue: row-sums (same band across all this segment's tiles)
        #pragma unroll
        for (int m = 0; m < 4; ++m)
            #pragma unroll
            for (int r = 0; r < 4; ++r) {
                float v = rowsum[m][r];
                v += __shfl_xor(v, 1);
                v += __shfl_xor(v, 2);
                v += __shfl_xor(v, 4);
                v += __shfl_xor(v, 8);
                if (l15 == 0) rowred[w * 64 + m * 16 + lg * 4 + r] = v;
            }
        __syncthreads();
        rowacc[(size_t)rowSlot * N_ROWS + r0 + tid] = rowred[tid];

        t = rowStart + cbE;
    }
}

// ---------------- finalize: loss = sum_i log( sum_k rowacc[k][i] ) / 100 ----------------
__global__ void finalize_kernel(const float* __restrict__ rowacc, float* __restrict__ out) {
    int i = blockIdx.x * 256 + threadIdx.x;      // one row per thread, 64 blocks
    float s = 0.f;
    #pragma unroll 8
    for (int k = 0; k < NSLOT; ++k) s += rowacc[(size_t)k * N_ROWS + i];
    float v = logf(s);
    #pragma unroll
    for (int off = 1; off < 64; off <<= 1) v += __shfl_xor(v, off);
    __shared__ float red[4];
    if ((threadIdx.x & 63) == 0) red[threadIdx.x >> 6] = v;
    __syncthreads();
    if (threadIdx.x == 0)
        atomicAdd(out, (red[0] + red[1] + red[2] + red[3]) * 0.01f);
}

extern "C" void kernel_launch(void* const* d_in, const int* in_sizes, int n_in,
                              void* d_out, int out_size, void* d_ws, size_t ws_size,
                              hipStream_t stream) {
    const float* x = (const float*)d_in[0];
    unsigned short* xb = (unsigned short*)d_ws;                           // 8 MB bf16 (pre-scaled)
    float* rowacc = (float*)((char*)d_ws + (size_t)N_ROWS * KD * 2);      // 96 x 16384 f32 (6 MB)
    float* out = (float*)d_out;

    convert_kernel<<<(N_ROWS * KD) / (256 * 4), 256, 0, stream>>>(x, xb, rowacc, out);
    simloss_main<<<NBLK, 256, 0, stream>>>(xb, rowacc);
    finalize_kernel<<<N_ROWS / 256, 256, 0, stream>>>(rowacc, out);
}